// Round 3
// baseline (1022.963 us; speedup 1.0000x reference)
//
#include <hip/hip_runtime.h>

typedef unsigned short u16;
typedef __attribute__((ext_vector_type(8))) short bh8;     // 8 bf16 MFMA A/B frag
typedef __attribute__((ext_vector_type(4))) float f4;      // MFMA C/D frag / float4
typedef __attribute__((ext_vector_type(4))) unsigned short us4;

#define T_SEQ 2048
#define NHEADS 16
#define DHEAD 64
#define WIN 256

__device__ __forceinline__ float bf2f(u16 u) {
  union { unsigned int i; float f; } v; v.i = ((unsigned int)u) << 16; return v.f;
}
__device__ __forceinline__ u16 f2bf(float f) {
  unsigned int u = __float_as_uint(f);
  u = u + 0x7fffu + ((u >> 16) & 1u);   // RNE
  return (u16)(u >> 16);
}

// ---------------- dtype detect: 1 if input is plausibly fp32, else 0 (bf16) ----------
__global__ void detect_dtype(const void* x, int* flag) {
  if (threadIdx.x == 0 && blockIdx.x == 0) {
    const float* xf = (const float*)x;
    int ok = 1;
    for (int i = 0; i < 128; ++i) {
      float v = xf[i];
      float a = fabsf(v);
      if (!(a < 64.f)) { ok = 0; break; }            // catches NaN/Inf/huge
      if (!(v == 0.f || a > 1e-30f)) { ok = 0; break; }
    }
    *flag = ok;
  }
}

// ---------------- transpose+convert: in (R x C, fp32-or-bf16 per flag) -> bf16 (C x R) ----
__global__ void transpose_conv(const void* __restrict__ in, u16* __restrict__ out,
                               int R, int C, const int* __restrict__ flag) {
  __shared__ alignas(16) u16 tile[32][33];
  const int isf = *flag;
  const int tx = threadIdx.x, ty = threadIdx.y;
  const int x  = blockIdx.x * 32 + tx;
  const int y0 = blockIdx.y * 32;
  #pragma unroll
  for (int i = ty; i < 32; i += 8) {
    u16 v;
    if (isf) v = f2bf(((const float*)in)[(size_t)(y0 + i) * C + x]);
    else     v = ((const u16*)in)[(size_t)(y0 + i) * C + x];
    tile[i][tx] = v;
  }
  __syncthreads();
  const int ox  = y0 + tx;
  const int oy0 = blockIdx.x * 32;
  #pragma unroll
  for (int i = ty; i < 32; i += 8)
    out[(size_t)(oy0 + i) * R + ox] = tile[tx][i];
}

// ---------------- bf16 GEMM, C[M,N] = A[M,K(lda)] * Bt[N,K]^T ----------------
// ADYN: A dtype follows flag (fp32 when flag). CDYN: C store dtype follows flag.
// Bt is always canonical bf16. Conservative register->LDS staging.
template<bool ADYN, bool CDYN>
__global__ __launch_bounds__(256) void gemm_bt(
    const void* __restrict__ A, const u16* __restrict__ Bt,
    void* __restrict__ C, int N, int K, int lda, int ldc,
    const int* __restrict__ flag)
{
  __shared__ alignas(16) u16 As[128 * 32];   // 8 KB
  __shared__ alignas(16) u16 Bs[128 * 32];   // 8 KB

  const int isf  = *flag;
  const int tid  = threadIdx.x;
  const int lane = tid & 63;
  const int w    = tid >> 6;
  const int wm   = (w >> 1) * 64;
  const int wn   = (w & 1) * 64;
  const int quad = lane >> 4;
  const int l16  = lane & 15;
  const int row0 = blockIdx.y * 128;
  const int col0 = blockIdx.x * 128;

  f4 acc[4][4] = {};

  // staging: thread t -> row t/4, 16B chunk t%4
  const int srow = tid >> 2;
  const int scol = (tid & 3) * 8;
  const size_t aoff0 = (size_t)(row0 + srow) * lda + scol;
  const size_t aoff1 = (size_t)(row0 + 64 + srow) * lda + scol;
  const u16* gB0 = Bt + (size_t)(col0 + srow) * K + scol;
  const u16* gB1 = Bt + (size_t)(col0 + 64 + srow) * K + scol;
  u16* lA0 = As + tid * 8;
  u16* lA1 = As + 2048 + tid * 8;
  u16* lB0 = Bs + tid * 8;
  u16* lB1 = Bs + 2048 + tid * 8;

  const bool af32 = ADYN && isf;

  for (int k0 = 0; k0 < K; k0 += 32) {
    bh8 a0, a1;
    if (af32) {
      const float* Af = (const float*)A;
      f4 u00 = *(const f4*)(Af + aoff0 + k0);
      f4 u01 = *(const f4*)(Af + aoff0 + k0 + 4);
      f4 u10 = *(const f4*)(Af + aoff1 + k0);
      f4 u11 = *(const f4*)(Af + aoff1 + k0 + 4);
      #pragma unroll
      for (int u = 0; u < 4; ++u) {
        a0[u]     = (short)f2bf(u00[u]);
        a0[u + 4] = (short)f2bf(u01[u]);
        a1[u]     = (short)f2bf(u10[u]);
        a1[u + 4] = (short)f2bf(u11[u]);
      }
    } else {
      const u16* A16 = (const u16*)A;
      a0 = *(const bh8*)(A16 + aoff0 + k0);
      a1 = *(const bh8*)(A16 + aoff1 + k0);
    }
    bh8 b0 = *(const bh8*)(gB0 + k0);
    bh8 b1 = *(const bh8*)(gB1 + k0);
    __syncthreads();                 // prev-iter LDS reads complete before overwrite
    *(bh8*)lA0 = a0; *(bh8*)lA1 = a1;
    *(bh8*)lB0 = b0; *(bh8*)lB1 = b1;
    __syncthreads();

    bh8 af[4], bf[4];
    #pragma unroll
    for (int i = 0; i < 4; ++i)
      af[i] = *(const bh8*)(As + (wm + i * 16 + l16) * 32 + quad * 8);
    #pragma unroll
    for (int j = 0; j < 4; ++j)
      bf[j] = *(const bh8*)(Bs + (wn + j * 16 + l16) * 32 + quad * 8);
    #pragma unroll
    for (int i = 0; i < 4; ++i)
      #pragma unroll
      for (int j = 0; j < 4; ++j)
        acc[i][j] = __builtin_amdgcn_mfma_f32_16x16x32_bf16(af[i], bf[j], acc[i][j], 0, 0, 0);
  }

  // C/D layout: col = lane&15, row = quad*4 + reg
  const bool cf32 = CDYN && isf;
  #pragma unroll
  for (int i = 0; i < 4; ++i) {
    #pragma unroll
    for (int j = 0; j < 4; ++j) {
      const int rb = row0 + wm + i * 16 + quad * 4;
      const int cc = col0 + wn + j * 16 + l16;
      #pragma unroll
      for (int r = 0; r < 4; ++r) {
        if (cf32) ((float*)C)[(size_t)(rb + r) * ldc + cc] = acc[i][j][r];
        else      ((u16*)C)[(size_t)(rb + r) * ldc + cc]   = f2bf(acc[i][j][r]);
      }
    }
  }
}

// ---------------- sliding-window attention (canonical bf16 qkv workspace) ------------
// qkv: [B*T, 3072] bf16 (q +0, k +1024, v +2048; head h at +h*64)
// Output written in-place into the q-channel (each block's Q rows are staged to LDS
// before any write; no other block reads another block's q-channel region).
__global__ __launch_bounds__(256) void attn_kernel(u16* __restrict__ qkv)
{
  __shared__ alignas(16) u16 Ks[320 * 72];   // K window, row stride 72
  __shared__ alignas(16) u16 Vt[64 * 324];   // V transposed: [d][row]
  __shared__ alignas(16) u16 Qs[64 * 72];
  __shared__ alignas(16) float Ps[4][324];   // per-wave probabilities, abs-row indexed

  const int tid  = threadIdx.x;
  const int lane = tid & 63;
  const int w    = tid >> 6;
  const int qb = blockIdx.x, h = blockIdx.y, b = blockIdx.z;
  const int qs = qb * 64;
  const int ks = (qs - (WIN - 1)) > 0 ? (qs - (WIN - 1)) : 0;
  const int nrows = qs + 64 - ks;            // <= 319

  // ---- stage K, Q, V^T ----
  {
    const int c8 = (tid & 7) * 8;
    for (int r = tid >> 3; r < nrows; r += 32)
      *(bh8*)&Ks[r * 72 + c8] =
          *(const bh8*)&qkv[((size_t)(b * T_SEQ + ks + r)) * 3072 + 1024 + h * 64 + c8];
    for (int r = tid >> 3; r < 64; r += 32)
      *(bh8*)&Qs[r * 72 + c8] =
          *(const bh8*)&qkv[((size_t)(b * T_SEQ + qs + r)) * 3072 + h * 64 + c8];
    const int npad = nrows + 3;              // zero-pad tail rows for 4-wide PV reads
    for (int r = tid >> 3; r < npad; r += 32) {
      bh8 v = {};
      if (r < nrows)
        v = *(const bh8*)&qkv[((size_t)(b * T_SEQ + ks + r)) * 3072 + 2048 + h * 64 + c8];
      #pragma unroll
      for (int u = 0; u < 8; ++u) Vt[(c8 + u) * 324 + r] = (u16)v[u];
    }
  }
  __syncthreads();

  // wave w handles queries w*16 .. w*16+15
  for (int t = 0; t < 16; ++t) {
    const int ql  = w * 16 + t;
    const int i   = qs + ql;
    const int jlo = (i - (WIN - 1)) > 0 ? (i - (WIN - 1)) : 0;
    const int rlo = jlo - ks;                // 0..63
    const int cnt = i - jlo + 1;             // 1..256

    float qreg[DHEAD];
    #pragma unroll
    for (int d = 0; d < DHEAD; d += 8) {
      bh8 qv = *(const bh8*)&Qs[ql * 72 + d];
      #pragma unroll
      for (int u = 0; u < 8; ++u) qreg[d + u] = bf2f((u16)qv[u]);
    }

    // QK^T: lane handles keys rlo + s4*64 + lane
    float sc[4];
    #pragma unroll
    for (int s4 = 0; s4 < 4; ++s4) {
      const int kk = s4 * 64 + lane;
      if (kk < cnt) {
        const int rk = rlo + kk;
        float a = 0.f;
        #pragma unroll
        for (int d = 0; d < DHEAD; d += 8) {
          bh8 kv = *(const bh8*)&Ks[rk * 72 + d];
          #pragma unroll
          for (int u = 0; u < 8; ++u) a += qreg[d + u] * bf2f((u16)kv[u]);
        }
        sc[s4] = a * 0.125f;
      } else sc[s4] = -1e30f;
    }

    float m = fmaxf(fmaxf(sc[0], sc[1]), fmaxf(sc[2], sc[3]));
    #pragma unroll
    for (int off = 32; off; off >>= 1) m = fmaxf(m, __shfl_xor(m, off));
    float p[4], lsum = 0.f;
    #pragma unroll
    for (int s4 = 0; s4 < 4; ++s4) {
      const int kk = s4 * 64 + lane;
      p[s4] = (kk < cnt) ? __expf(sc[s4] - m) : 0.f;
      lsum += p[s4];
    }
    #pragma unroll
    for (int off = 32; off; off >>= 1) lsum += __shfl_xor(lsum, off);
    const float inv = 1.f / lsum;

    const int r0 = rlo & ~3;
    if (lane < 4) { Ps[w][r0 + lane] = 0.f; Ps[w][rlo + 256 + lane] = 0.f; }
    #pragma unroll
    for (int s4 = 0; s4 < 4; ++s4)
      Ps[w][rlo + s4 * 64 + lane] = p[s4] * inv;

    // PV: lane = d; 4 keys per iteration
    const int r1 = rlo + cnt - 1;
    float o = 0.f;
    for (int r = r0; r <= r1; r += 4) {
      float p0 = Ps[w][r], p1 = Ps[w][r + 1], p2 = Ps[w][r + 2], p3 = Ps[w][r + 3];
      us4 vv = *(const us4*)&Vt[lane * 324 + r];
      o += p0 * bf2f(vv[0]) + p1 * bf2f(vv[1]) +
           p2 * bf2f(vv[2]) + p3 * bf2f(vv[3]);
    }
    qkv[((size_t)(b * T_SEQ + i)) * 3072 + h * 64 + lane] = f2bf(o);  // in-place (q slot)
  }
}

// ---------------- launcher ----------------
extern "C" void kernel_launch(void* const* d_in, const int* in_sizes, int n_in,
                              void* d_out, int out_size, void* d_ws, size_t ws_size,
                              hipStream_t stream) {
  const void* x     = d_in[0];   // [8192, 1024]  fp32 or bf16 (auto-detected)
  const void* w_qkv = d_in[1];   // [1024, 3072]
  const void* w_out = d_in[2];   // [1024, 1024]

  char* p = (char*)d_ws;
  u16* qkv   = (u16*)p; p += (size_t)8192 * 3072 * 2;   // 50.3 MB
  u16* wqkvT = (u16*)p; p += (size_t)3072 * 1024 * 2;   //  6.3 MB
  u16* woutT = (u16*)p; p += (size_t)1024 * 1024 * 2;   //  2.1 MB
  int* flag  = (int*)p;                                  // +4 B

  detect_dtype<<<1, 64, 0, stream>>>(x, flag);

  dim3 tb(32, 8);
  transpose_conv<<<dim3(96, 32), tb, 0, stream>>>(w_qkv, wqkvT, 1024, 3072, flag);
  transpose_conv<<<dim3(32, 32), tb, 0, stream>>>(w_out, woutT, 1024, 1024, flag);

  // qkv = x @ w_qkv  (A dtype per flag, C canonical bf16)
  gemm_bt<true, false><<<dim3(24, 64), 256, 0, stream>>>(
      x, wqkvT, qkv, 3072, 1024, 1024, 3072, flag);

  // attention, writes into q-channel of qkv (bf16)
  attn_kernel<<<dim3(32, NHEADS, 4), 256, 0, stream>>>(qkv);

  // out = att @ w_out  (A canonical bf16 at lda=3072, C dtype per flag)
  gemm_bt<false, true><<<dim3(8, 64), 256, 0, stream>>>(
      qkv, woutT, d_out, 1024, 1024, 3072, 1024, flag);
}

// Round 4
// 267.267 us; speedup vs baseline: 3.8275x; 3.8275x over previous
//
#include <hip/hip_runtime.h>

typedef unsigned short u16;
typedef __attribute__((ext_vector_type(8))) short bh8;     // 8 bf16 MFMA A/B frag
typedef __attribute__((ext_vector_type(4))) float f4;      // MFMA C/D frag / float4
typedef __attribute__((ext_vector_type(4))) unsigned short us4;

#define T_SEQ 2048
#define NHEADS 16
#define DHEAD 64
#define WIN 256

__device__ __forceinline__ float bf2f(u16 u) {
  union { unsigned int i; float f; } v; v.i = ((unsigned int)u) << 16; return v.f;
}
__device__ __forceinline__ u16 f2bf(float f) {
  unsigned int u = __float_as_uint(f);
  u = u + 0x7fffu + ((u >> 16) & 1u);   // RNE
  return (u16)(u >> 16);
}

// ---------------- dtype detect: 1 if input is plausibly fp32, else 0 (bf16) ----------
__global__ void detect_dtype(const void* x, int* flag) {
  if (threadIdx.x == 0 && blockIdx.x == 0) {
    const float* xf = (const float*)x;
    int ok = 1;
    for (int i = 0; i < 128; ++i) {
      float v = xf[i];
      float a = fabsf(v);
      if (!(a < 64.f)) { ok = 0; break; }
      if (!(v == 0.f || a > 1e-30f)) { ok = 0; break; }
    }
    *flag = ok;
  }
}

// ---------------- x convert: fp32-or-bf16 (per flag) -> canonical bf16 --------------
__global__ void xconv(const void* __restrict__ in, u16* __restrict__ out,
                      const int* __restrict__ flag, int n8) {
  const int i = blockIdx.x * 256 + threadIdx.x;
  if (i >= n8) return;
  const size_t e = (size_t)i * 8;
  if (*flag) {
    const float* f = (const float*)in;
    us4 o0, o1;
    #pragma unroll
    for (int u = 0; u < 4; ++u) { o0[u] = f2bf(f[e + u]); o1[u] = f2bf(f[e + 4 + u]); }
    *(us4*)&out[e] = o0; *(us4*)&out[e + 4] = o1;
  } else {
    *(us4*)&out[e]     = *(const us4*)&((const u16*)in)[e];
    *(us4*)&out[e + 4] = *(const us4*)&((const u16*)in)[e + 4];
  }
}

// ---------------- transpose+convert: in (R x C, fp32-or-bf16 per flag) -> bf16 (C x R) ----
__global__ void transpose_conv(const void* __restrict__ in, u16* __restrict__ out,
                               int R, int C, const int* __restrict__ flag) {
  __shared__ alignas(16) u16 tile[32][33];
  const int isf = *flag;
  const int tx = threadIdx.x, ty = threadIdx.y;
  const int x  = blockIdx.x * 32 + tx;
  const int y0 = blockIdx.y * 32;
  #pragma unroll
  for (int i = ty; i < 32; i += 8) {
    u16 v;
    if (isf) v = f2bf(((const float*)in)[(size_t)(y0 + i) * C + x]);
    else     v = ((const u16*)in)[(size_t)(y0 + i) * C + x];
    tile[i][tx] = v;
  }
  __syncthreads();
  const int ox  = y0 + tx;
  const int oy0 = blockIdx.x * 32;
  #pragma unroll
  for (int i = ty; i < 32; i += 8)
    out[(size_t)(oy0 + i) * R + ox] = tile[tx][i];
}

// ---------------- bf16 GEMM, C[M,N] = A[M,K(lda)] * Bt[N,K]^T ----------------
template<bool ADYN, bool CDYN>
__global__ __launch_bounds__(256) void gemm_bt(
    const void* __restrict__ A, const u16* __restrict__ Bt,
    void* __restrict__ C, int N, int K, int lda, int ldc,
    const int* __restrict__ flag)
{
  __shared__ alignas(16) u16 As[128 * 32];
  __shared__ alignas(16) u16 Bs[128 * 32];

  const int isf  = ADYN ? *flag : 0;
  const int tid  = threadIdx.x;
  const int lane = tid & 63;
  const int w    = tid >> 6;
  const int wm   = (w >> 1) * 64;
  const int wn   = (w & 1) * 64;
  const int quad = lane >> 4;
  const int l16  = lane & 15;
  const int row0 = blockIdx.y * 128;
  const int col0 = blockIdx.x * 128;

  f4 acc[4][4] = {};

  const int srow = tid >> 2;
  const int scol = (tid & 3) * 8;
  const size_t aoff0 = (size_t)(row0 + srow) * lda + scol;
  const size_t aoff1 = (size_t)(row0 + 64 + srow) * lda + scol;
  const u16* gB0 = Bt + (size_t)(col0 + srow) * K + scol;
  const u16* gB1 = Bt + (size_t)(col0 + 64 + srow) * K + scol;
  u16* lA0 = As + tid * 8;
  u16* lA1 = As + 2048 + tid * 8;
  u16* lB0 = Bs + tid * 8;
  u16* lB1 = Bs + 2048 + tid * 8;

  const bool af32 = ADYN && isf;

  for (int k0 = 0; k0 < K; k0 += 32) {
    bh8 a0, a1;
    if (af32) {
      const float* Af = (const float*)A;
      f4 u00 = *(const f4*)(Af + aoff0 + k0);
      f4 u01 = *(const f4*)(Af + aoff0 + k0 + 4);
      f4 u10 = *(const f4*)(Af + aoff1 + k0);
      f4 u11 = *(const f4*)(Af + aoff1 + k0 + 4);
      #pragma unroll
      for (int u = 0; u < 4; ++u) {
        a0[u]     = (short)f2bf(u00[u]);
        a0[u + 4] = (short)f2bf(u01[u]);
        a1[u]     = (short)f2bf(u10[u]);
        a1[u + 4] = (short)f2bf(u11[u]);
      }
    } else {
      const u16* A16 = (const u16*)A;
      a0 = *(const bh8*)(A16 + aoff0 + k0);
      a1 = *(const bh8*)(A16 + aoff1 + k0);
    }
    bh8 b0 = *(const bh8*)(gB0 + k0);
    bh8 b1 = *(const bh8*)(gB1 + k0);
    __syncthreads();
    *(bh8*)lA0 = a0; *(bh8*)lA1 = a1;
    *(bh8*)lB0 = b0; *(bh8*)lB1 = b1;
    __syncthreads();

    bh8 af[4], bf[4];
    #pragma unroll
    for (int i = 0; i < 4; ++i)
      af[i] = *(const bh8*)(As + (wm + i * 16 + l16) * 32 + quad * 8);
    #pragma unroll
    for (int j = 0; j < 4; ++j)
      bf[j] = *(const bh8*)(Bs + (wn + j * 16 + l16) * 32 + quad * 8);
    #pragma unroll
    for (int i = 0; i < 4; ++i)
      #pragma unroll
      for (int j = 0; j < 4; ++j)
        acc[i][j] = __builtin_amdgcn_mfma_f32_16x16x32_bf16(af[i], bf[j], acc[i][j], 0, 0, 0);
  }

  const bool cf32 = CDYN && (*flag);
  #pragma unroll
  for (int i = 0; i < 4; ++i) {
    #pragma unroll
    for (int j = 0; j < 4; ++j) {
      const int rb = row0 + wm + i * 16 + quad * 4;
      const int cc = col0 + wn + j * 16 + l16;
      #pragma unroll
      for (int r = 0; r < 4; ++r) {
        if (cf32) ((float*)C)[(size_t)(rb + r) * ldc + cc] = acc[i][j][r];
        else      ((u16*)C)[(size_t)(rb + r) * ldc + cc]   = f2bf(acc[i][j][r]);
      }
    }
  }
}

// ---------------- MFMA flash-style sliding-window attention ----------------
// qkv: [B*T, 3072] bf16 (q +0, k +1024, v +2048; head h at +h*64).
// Output in-place into the q-channel (each block's Q staged to LDS first; blocks
// touch disjoint (row-chunk, head-column) regions of the q-channel).
// Per block: 64 queries of one (b,h); 5 key tiles of 64; online softmax.
__global__ __launch_bounds__(256) void attn_mfma(u16* __restrict__ qkv)
{
  __shared__ alignas(16) u16 Qs[64 * 72];
  __shared__ alignas(16) u16 Kt[64 * 72];
  // Vt: elem (d,k) at d*72 + ((k>>3)^(d>>3))*8 + (k&7)   (XOR chunk swizzle)
  __shared__ alignas(16) u16 Vt[64 * 72];
  // Ps: elem (q,k) at q*72 + ((k>>3)^((q>>3)&1))*8 + (k&7)
  __shared__ alignas(16) u16 Ps[64 * 72];

  const int tid  = threadIdx.x;
  const int lane = tid & 63;
  const int w    = tid >> 6;
  const int quad = lane >> 4;
  const int l16  = lane & 15;
  const int qb = blockIdx.x, h = blockIdx.y, b = blockIdx.z;
  const int qs = qb * 64;

  const u16* base = qkv + (size_t)b * T_SEQ * 3072 + h * 64;

  // ---- stage Q (one time) ----
  const int c8  = (tid & 7) * 8;
  const int r0s = tid >> 3;                 // 0..31
  #pragma unroll
  for (int r = r0s; r < 64; r += 32)
    *(bh8*)&Qs[r * 72 + c8] = *(const bh8*)&base[(size_t)(qs + r) * 3072 + c8];

  f4 Oc[4] = {};                            // 16 q x 64 d accumulator (C-layout)
  float mst[4] = {-1e30f, -1e30f, -1e30f, -1e30f};
  float lst[4] = {0.f, 0.f, 0.f, 0.f};

  const int tmin = (qb >= 4) ? 0 : (4 - qb);   // skip fully-negative key tiles

  for (int t = tmin; t < 5; ++t) {
    const int kt0 = qs - 256 + t * 64;      // >= 0 by tmin
    __syncthreads();                        // prior tile's Kt/Vt readers done

    // ---- stage K tile + V tile (transposed, swizzled) ----
    #pragma unroll
    for (int r = r0s; r < 64; r += 32) {
      *(bh8*)&Kt[r * 72 + c8] =
          *(const bh8*)&base[(size_t)(kt0 + r) * 3072 + 1024 + c8];
      bh8 v = *(const bh8*)&base[(size_t)(kt0 + r) * 3072 + 2048 + c8];
      const int kc = r >> 3, ki = r & 7;
      #pragma unroll
      for (int u = 0; u < 8; ++u) {
        const int d = c8 + u;
        Vt[d * 72 + ((kc ^ (d >> 3)) << 3) + ki] = (u16)v[u];
      }
    }
    __syncthreads();

    // ---- QK^T (wave w: queries w*16..w*16+15, all 64 keys of tile) ----
    const int qrow = (w * 16 + l16) * 72;
    bh8 qa0 = *(const bh8*)&Qs[qrow + quad * 8];
    bh8 qa1 = *(const bh8*)&Qs[qrow + 32 + quad * 8];
    f4 S[4];
    #pragma unroll
    for (int kb = 0; kb < 4; ++kb) {
      const int krow = (kb * 16 + l16) * 72;
      bh8 kf0 = *(const bh8*)&Kt[krow + quad * 8];
      bh8 kf1 = *(const bh8*)&Kt[krow + 32 + quad * 8];
      f4 s = {};
      s = __builtin_amdgcn_mfma_f32_16x16x32_bf16(qa0, kf0, s, 0, 0, 0);
      s = __builtin_amdgcn_mfma_f32_16x16x32_bf16(qa1, kf1, s, 0, 0, 0);
      S[kb] = s;
    }

    // ---- mask + scale + tile max ----
    const int iq0 = qs + w * 16 + quad * 4;       // query of reg rr: iq0+rr
    float tmax[4] = {-1e30f, -1e30f, -1e30f, -1e30f};
    #pragma unroll
    for (int kb = 0; kb < 4; ++kb) {
      const int j = kt0 + kb * 16 + l16;
      #pragma unroll
      for (int rr = 0; rr < 4; ++rr) {
        const int i = iq0 + rr;
        float s = S[kb][rr] * 0.125f;
        const bool ok = (j <= i) && (j > i - WIN);
        s = ok ? s : -1e30f;
        S[kb][rr] = s;
        tmax[rr] = fmaxf(tmax[rr], s);
      }
    }
    #pragma unroll
    for (int off = 1; off < 16; off <<= 1)
      #pragma unroll
      for (int rr = 0; rr < 4; ++rr)
        tmax[rr] = fmaxf(tmax[rr], __shfl_xor(tmax[rr], off));

    // ---- online-softmax update ----
    float alpha[4], rsum[4];
    #pragma unroll
    for (int rr = 0; rr < 4; ++rr) {
      const float mnew = fmaxf(mst[rr], tmax[rr]);
      alpha[rr] = __expf(mst[rr] - mnew);
      mst[rr] = mnew;
      rsum[rr] = 0.f;
    }

    // ---- P = exp(S-m) (masked->0), write bf16 to Ps (swizzled C-layout) ----
    const int swq = quad >> 1;                    // ((quad*4+rr)>>3)&1
    #pragma unroll
    for (int kb = 0; kb < 4; ++kb) {
      const int kc = (kb * 2 + (l16 >> 3)) ^ 0;   // k>>3
      const int ki = l16 & 7;
      #pragma unroll
      for (int rr = 0; rr < 4; ++rr) {
        const float sv = S[kb][rr];
        const float p = (sv > -0.5e30f) ? __expf(sv - mst[rr]) : 0.f;
        rsum[rr] += p;
        const int q = w * 16 + quad * 4 + rr;
        Ps[q * 72 + ((kc ^ swq) << 3) + ki] = f2bf(p);
      }
    }
    #pragma unroll
    for (int off = 1; off < 16; off <<= 1)
      #pragma unroll
      for (int rr = 0; rr < 4; ++rr)
        rsum[rr] += __shfl_xor(rsum[rr], off);
    #pragma unroll
    for (int rr = 0; rr < 4; ++rr)
      lst[rr] = lst[rr] * alpha[rr] + rsum[rr];

    // ---- rescale O, then PV ----
    #pragma unroll
    for (int db = 0; db < 4; ++db)
      #pragma unroll
      for (int rr = 0; rr < 4; ++rr)
        Oc[db][rr] *= alpha[rr];

    {
      const int q = w * 16 + l16;
      const int sw = (q >> 3) & 1;                // = (l16>>3)&1
      bh8 pa0 = *(const bh8*)&Ps[q * 72 + (((0 + quad) ^ sw) << 3)];
      bh8 pa1 = *(const bh8*)&Ps[q * 72 + (((4 + quad) ^ sw) << 3)];
      #pragma unroll
      for (int db = 0; db < 4; ++db) {
        const int d = db * 16 + l16;
        const int dsw = d >> 3;
        bh8 vb0 = *(const bh8*)&Vt[d * 72 + (((0 + quad) ^ dsw) << 3)];
        bh8 vb1 = *(const bh8*)&Vt[d * 72 + (((4 + quad) ^ dsw) << 3)];
        Oc[db] = __builtin_amdgcn_mfma_f32_16x16x32_bf16(pa0, vb0, Oc[db], 0, 0, 0);
        Oc[db] = __builtin_amdgcn_mfma_f32_16x16x32_bf16(pa1, vb1, Oc[db], 0, 0, 0);
      }
    }
  }

  // ---- epilogue: O/l -> q-channel (in-place) ----
  u16* obase = (u16*)base;
  #pragma unroll
  for (int rr = 0; rr < 4; ++rr) {
    const int i = qs + w * 16 + quad * 4 + rr;
    const float inv = 1.f / lst[rr];
    #pragma unroll
    for (int db = 0; db < 4; ++db)
      obase[(size_t)i * 3072 + db * 16 + l16] = f2bf(Oc[db][rr] * inv);
  }
}

// ---------------- launcher ----------------
extern "C" void kernel_launch(void* const* d_in, const int* in_sizes, int n_in,
                              void* d_out, int out_size, void* d_ws, size_t ws_size,
                              hipStream_t stream) {
  const void* x     = d_in[0];   // [8192, 1024]  fp32 or bf16 (auto-detected)
  const void* w_qkv = d_in[1];   // [1024, 3072]
  const void* w_out = d_in[2];   // [1024, 1024]

  const size_t SZ_QKV  = (size_t)8192 * 3072 * 2;
  const size_t SZ_XBF  = (size_t)8192 * 1024 * 2;
  const size_t SZ_WQ   = (size_t)3072 * 1024 * 2;
  const size_t SZ_WO   = (size_t)1024 * 1024 * 2;

  char* p = (char*)d_ws;
  u16* qkv   = (u16*)p; p += SZ_QKV;
  u16* wqkvT = (u16*)p; p += SZ_WQ;
  u16* woutT = (u16*)p; p += SZ_WO;
  int* flag  = (int*)p; p += 16;
  u16* xbf   = (u16*)p;                     // optional region
  const bool have_x = ws_size >= (SZ_QKV + SZ_WQ + SZ_WO + 16 + SZ_XBF);

  detect_dtype<<<1, 64, 0, stream>>>(x, flag);

  dim3 tb(32, 8);
  transpose_conv<<<dim3(96, 32), tb, 0, stream>>>(w_qkv, wqkvT, 1024, 3072, flag);
  transpose_conv<<<dim3(32, 32), tb, 0, stream>>>(w_out, woutT, 1024, 1024, flag);

  if (have_x) {
    xconv<<<dim3(4096), 256, 0, stream>>>(x, xbf, flag, 1048576);
    gemm_bt<false, false><<<dim3(24, 64), 256, 0, stream>>>(
        xbf, wqkvT, qkv, 3072, 1024, 1024, 3072, flag);
  } else {
    gemm_bt<true, false><<<dim3(24, 64), 256, 0, stream>>>(
        x, wqkvT, qkv, 3072, 1024, 1024, 3072, flag);
  }

  attn_mfma<<<dim3(32, NHEADS, 4), 256, 0, stream>>>(qkv);

  gemm_bt<false, true><<<dim3(8, 64), 256, 0, stream>>>(
      qkv, woutT, d_out, 1024, 1024, 3072, 1024, flag);
}